// Round 9
// baseline (1048.679 us; speedup 1.0000x reference)
//
#include <hip/hip_runtime.h>
#include <stdint.h>

#define HDIM 768
#define IDIM 3072
#define NROWS 25216   // 128*197
#define RPB 8         // rows per block in fused kernel
#define TPB 512       // threads per block (fused)
#define KCH 6         // IDIM / TPB

// ---------------------------------------------------------------------------
// Pass 1: pack W sign bits + fold scales.
//   wbits layout: [i][w=0..24] u32; word w covers h=w*32..w*32+31,
//   bit k <-> h=w*32+k, bit=1 <=> W>0.
//   c0[i] = sum|W[i,:]| + b[i]      (alpha*768 + b)
//   c1[i] = sum|W[i,:]| * 2/768     (2*alpha)
//   y = c0 - c1 * popcount_mismatch
// ---------------------------------------------------------------------------
__global__ __launch_bounds__(256) void wprep_kernel(
    const float* __restrict__ W, const float* __restrict__ bias,
    uint32_t* __restrict__ wbits, float* __restrict__ c0, float* __restrict__ c1)
{
    const int wv   = threadIdx.x >> 6;
    const int lane = threadIdx.x & 63;
    const int i    = blockIdx.x * 4 + wv;
    const float* wr = W + (size_t)i * HDIM;

    float sabs = 0.f;
    uint32_t myword = 0;
    #pragma unroll
    for (int c = 0; c < 12; ++c) {
        float w = wr[c * 64 + lane];
        sabs += fabsf(w);
        unsigned long long mask = __ballot(w > 0.f);
        if (lane == 2 * c)     myword = (uint32_t)mask;
        if (lane == 2 * c + 1) myword = (uint32_t)(mask >> 32);
    }
    #pragma unroll
    for (int m = 32; m; m >>= 1) sabs += __shfl_xor(sabs, m, 64);

    if (lane < 24)
        wbits[(size_t)i * 24 + lane] = myword;
    if (lane == 0) {
        c0[i] = sabs + bias[i];
        c1[i] = sabs * (2.0f / 768.0f);
    }
}

// ---------------------------------------------------------------------------
// Pass 2: fused binarize -> xnor-popcount GEMM -> LayerNorm -> concat
//         residual -> RPReLU.  One block = 8 rows, 512 threads (8 waves).
//
// Loop order: wg OUTER. Per wg, the 8 rows' x-words are read ONCE from LDS
// (8 broadcast ds_read_b128, conflict-free), then 6 k-chunks each load one
// wbits dwordx4 and update 8 int accumulators. Total per thread:
// 48 ds_read_b128 + 36 global dwordx4 + 2304 xor/popc — all-static indexing,
// no anti-CSE hacks needed (every load has a distinct address).
// ---------------------------------------------------------------------------
__global__ __launch_bounds__(TPB) void fused_kernel(
    const float* __restrict__ hid, const float* __restrict__ move,
    const uint32_t* __restrict__ wbits,
    const float* __restrict__ c0, const float* __restrict__ c1,
    const float* __restrict__ gamma, const float* __restrict__ beta,
    const float* __restrict__ move1, const float* __restrict__ pal,
    const float* __restrict__ move2, float* __restrict__ out)
{
    __shared__ float hlds[RPB * HDIM];                        // 24 KB residual
    __shared__ __attribute__((aligned(16))) uint32_t xlds[RPB][24]; // 768 B
    __shared__ float red[8][RPB][2];                          // LN partials
    __shared__ float musd[RPB][2];                            // mu, rstd

    const int tid  = threadIdx.x;
    const int wv   = tid >> 6;
    const int lane = tid & 63;
    const size_t row0 = (size_t)blockIdx.x * RPB;

    // ---- stage 8 hidden rows into LDS (coalesced float4) ----
    {
        const float4* src = (const float4*)(hid + row0 * HDIM);
        float4* dst = (float4*)hlds;
        #pragma unroll
        for (int p = 0; p < 3; ++p) dst[tid + p * TPB] = src[tid + p * TPB];
    }
    __syncthreads();

    // ---- binarize: wave wv packs row wv (12 ballots x 64 lanes) ----
    #pragma unroll
    for (int j = 0; j < 12; ++j) {
        int h = j * 64 + lane;
        float v = hlds[wv * HDIM + h] + move[h];
        unsigned long long mask = __ballot(v > 0.f);
        if (lane == 0) xlds[wv][2 * j]     = (uint32_t)mask;
        if (lane == 1) xlds[wv][2 * j + 1] = (uint32_t)(mask >> 32);
    }
    __syncthreads();

    // ---- xnor-popcount GEMM, wg-outer ----
    int m[KCH][RPB];
    #pragma unroll
    for (int k = 0; k < KCH; ++k)
        #pragma unroll
        for (int r = 0; r < RPB; ++r) m[k][r] = 0;

    #pragma unroll
    for (int wg = 0; wg < 6; ++wg) {
        // 8 broadcast LDS reads: this wg's x-words for all 8 rows.
        uint4 xr[RPB];
        #pragma unroll
        for (int r = 0; r < RPB; ++r)
            xr[r] = *(const uint4*)&xlds[r][wg * 4];
        // 6 k-chunks: one wbits dwordx4 each, reused across 8 rows.
        #pragma unroll
        for (int k = 0; k < KCH; ++k) {
            const int i = k * TPB + tid;
            uint4 wb = *(const uint4*)(wbits + (size_t)i * 24 + wg * 4);
            #pragma unroll
            for (int r = 0; r < RPB; ++r) {
                m[k][r] += __popc(wb.x ^ xr[r].x) + __popc(wb.y ^ xr[r].y)
                         + __popc(wb.z ^ xr[r].z) + __popc(wb.w ^ xr[r].w);
            }
        }
    }

    // ---- y = c0 - c1*m, fold LN partial sums as we go ----
    float y[KCH][RPB];
    float s[RPB], q[RPB];
    #pragma unroll
    for (int r = 0; r < RPB; ++r) { s[r] = 0.f; q[r] = 0.f; }
    #pragma unroll
    for (int k = 0; k < KCH; ++k) {
        const int i = k * TPB + tid;
        const float C0 = c0[i], C1 = c1[i];
        #pragma unroll
        for (int r = 0; r < RPB; ++r) {
            float v = C0 - C1 * (float)m[k][r];   // alpha*(768-2m)+b
            y[k][r] = v;
            s[r] += v;
            q[r] += v * v;
        }
    }

    // ---- LayerNorm statistics (per row over 3072 i) ----
    #pragma unroll
    for (int r = 0; r < RPB; ++r) {
        float sr = s[r], qr = q[r];
        #pragma unroll
        for (int mm = 32; mm; mm >>= 1) {
            sr += __shfl_xor(sr, mm, 64);
            qr += __shfl_xor(qr, mm, 64);
        }
        if (lane == 0) { red[wv][r][0] = sr; red[wv][r][1] = qr; }
    }
    __syncthreads();
    if (tid < 64) {
        const int r = tid >> 3, w = tid & 7;
        float sr = red[w][r][0], qr = red[w][r][1];
        #pragma unroll
        for (int mm = 1; mm < 8; mm <<= 1) {
            sr += __shfl_xor(sr, mm, 64);
            qr += __shfl_xor(qr, mm, 64);
        }
        if (w == 0) {
            float mu  = sr * (1.0f / 3072.0f);
            float var = qr * (1.0f / 3072.0f) - mu * mu;
            musd[r][0] = mu;
            musd[r][1] = rsqrtf(var + 1e-12f);
        }
    }
    __syncthreads();

    float mur[RPB], rsr[RPB];
    #pragma unroll
    for (int r = 0; r < RPB; ++r) { mur[r] = musd[r][0]; rsr[r] = musd[r][1]; }

    // ---- epilogue: LN affine + concat residual + RPReLU + store ----
    #pragma unroll
    for (int k = 0; k < KCH; ++k) {
        const int i = k * TPB + tid;
        const float g  = gamma[i], be = beta[i];
        const float m1 = move1[i], pa = pal[i], m2 = move2[i];
        const int h = i % HDIM;                 // concat([hidden]*4) index
        #pragma unroll
        for (int r = 0; r < RPB; ++r) {
            float yn = (y[k][r] - mur[r]) * rsr[r] * g + be;
            float o  = yn + hlds[r * HDIM + h];
            float z  = o - m1;
            o = (z >= 0.f ? z : pa * z) + m2;
            out[(row0 + r) * IDIM + i] = o;
        }
    }
}

// ---------------------------------------------------------------------------
extern "C" void kernel_launch(void* const* d_in, const int* in_sizes, int n_in,
                              void* d_out, int out_size, void* d_ws, size_t ws_size,
                              hipStream_t stream)
{
    const float* hs    = (const float*)d_in[0];
    const float* W     = (const float*)d_in[1];
    const float* bias  = (const float*)d_in[2];
    const float* move  = (const float*)d_in[3];
    const float* gamma = (const float*)d_in[4];
    const float* beta  = (const float*)d_in[5];
    const float* move1 = (const float*)d_in[6];
    const float* pal   = (const float*)d_in[7];
    const float* move2 = (const float*)d_in[8];
    float* out = (float*)d_out;

    // workspace: wbits [IDIM*24 u32] = 294,912 B, then c0[IDIM], c1[IDIM]
    uint32_t* wbits = (uint32_t*)d_ws;
    float*    c0    = (float*)(wbits + (size_t)IDIM * 24);
    float*    c1    = c0 + IDIM;

    wprep_kernel<<<IDIM / 4, 256, 0, stream>>>(W, bias, wbits, c0, c1);
    fused_kernel<<<NROWS / RPB, TPB, 0, stream>>>(
        hs, move, wbits, c0, c1, gamma, beta, move1, pal, move2, out);
}